// Round 2
// baseline (12437.704 us; speedup 1.0000x reference)
//
#include <hip/hip_runtime.h>
#include <stdint.h>

// MambaBlock: DIM=1024, BATCH=8, SEQ=4096.
//   inp  = x @ W_in^T + b_in                  (fp32, parked in d_out)
//   gate = sigmoid(inp @ W_gate^T + b_gate)   (bf16 in ws)
//   u    = inp @ B^T                          (bf16 in ws)
//   scan: s_t = g*tanh(s_{t-1}@A^T + u_t) + (1-g)*inp_t   (fp32, tagged-granule LLC exchange)
//   out  = states @ W_out^T + b_out           (fp32 -> d_out)
//
// Scan v3 (= v2 + register pinning + fast tanh + reduce-scatter butterfly):
//   1024 waves; wave gw owns batch b=gw>>7 and cols j0..j0+7 (j0=(gw&127)*8).
//   A fragments are PINNED into 128 VGPRs via empty-asm opacification -- v2's
//   compiler sank the A loads into the t-loop (VGPR_Count=100 < 128 needed),
//   putting ~64 L2 loads on the per-step critical path.
//   State exchange unchanged from v2: slice[t][b][1024] fp32; each 8B granule
//   (2 cols) stored as one agent-scope atomic with a 4-bit epoch tag ((t&7)|8)
//   in the low float's mantissa nibble (2^-19 rel perturbation). Data+validity
//   atomic -> no fences, no flags, no barriers. memset(slice) kills stale tags.

#define D 1024
#define NBATCH 8
#define SEQ 4096
#define NROWS 32768  // NBATCH*SEQ

static constexpr size_t GATE_BYTES  = (size_t)NROWS * D * 2;          // 64 MiB bf16
static constexpr size_t U_BYTES     = (size_t)NROWS * D * 2;          // 64 MiB bf16
static constexpr size_t SLICE_BYTES = (size_t)SEQ * NBATCH * D * 4;   // 128 MiB fp32

__device__ __forceinline__ float bf2f(uint16_t h) {
  uint32_t u = ((uint32_t)h) << 16;
  return __builtin_bit_cast(float, u);
}
__device__ __forceinline__ uint16_t f2bf(float f) {
  uint32_t u = __builtin_bit_cast(uint32_t, f);
  u = u + 0x7fffu + ((u >> 16) & 1u);   // RNE
  return (uint16_t)(u >> 16);
}

// branch-free tanh: 1 - 2/(e^{2x}+1); saturates correctly at +-1 via inf/0.
__device__ __forceinline__ float fast_tanh(float x) {
  const float e = __expf(2.0f * x);
  return 1.0f - 2.0f / (e + 1.0f);
}

// ---------------- GEMM 1: inp = x @ W_in^T + b_in (fp32 out) ----------------
__global__ __launch_bounds__(256) void k_gemm_in(
    const float* __restrict__ X, const float* __restrict__ W,
    const float* __restrict__ bias, float* __restrict__ Y) {
  __shared__ float Xs[16][68];
  __shared__ float Ws[16][68];
  const int tid = threadIdx.x;
  const int m0 = blockIdx.y << 6, n0 = blockIdx.x << 6;
  const int tx = tid & 15, ty = tid >> 4;
  const int lr = tid >> 2, lk = (tid & 3) << 2;
  float acc[4][4] = {};
  const float* xp = X + (size_t)(m0 + lr) * D + lk;
  const float* wp = W + (size_t)(n0 + lr) * D + lk;
  for (int k0 = 0; k0 < D; k0 += 16) {
    float4 xv = *(const float4*)(xp + k0);
    float4 wv = *(const float4*)(wp + k0);
    __syncthreads();
    Xs[lk + 0][lr] = xv.x; Xs[lk + 1][lr] = xv.y; Xs[lk + 2][lr] = xv.z; Xs[lk + 3][lr] = xv.w;
    Ws[lk + 0][lr] = wv.x; Ws[lk + 1][lr] = wv.y; Ws[lk + 2][lr] = wv.z; Ws[lk + 3][lr] = wv.w;
    __syncthreads();
#pragma unroll
    for (int k = 0; k < 16; ++k) {
      float4 av = *(const float4*)&Xs[k][tx << 2];
      float4 bv = *(const float4*)&Ws[k][ty << 2];
      const float aa[4] = {av.x, av.y, av.z, av.w};
      const float bb[4] = {bv.x, bv.y, bv.z, bv.w};
#pragma unroll
      for (int i = 0; i < 4; ++i)
#pragma unroll
        for (int jj = 0; jj < 4; ++jj) acc[i][jj] += aa[i] * bb[jj];
    }
  }
  const int nc = n0 + (ty << 2);
#pragma unroll
  for (int i = 0; i < 4; ++i) {
    const int row = m0 + (tx << 2) + i;
    float4 o;
    o.x = acc[i][0] + bias[nc + 0];
    o.y = acc[i][1] + bias[nc + 1];
    o.z = acc[i][2] + bias[nc + 2];
    o.w = acc[i][3] + bias[nc + 3];
    *(float4*)&Y[(size_t)row * D + nc] = o;
  }
}

// ------- GEMM 2 (fused): gate = sigmoid(inp@Wg^T + bg), u = inp@B^T (bf16 out) -------
__global__ __launch_bounds__(256) void k_gemm_gate_u(
    const float* __restrict__ X, const float* __restrict__ Wg,
    const float* __restrict__ bg, const float* __restrict__ Bu,
    uint16_t* __restrict__ G, uint16_t* __restrict__ U) {
  __shared__ float Xs[16][68];
  __shared__ float Wgs[16][68];
  __shared__ float Wus[16][68];
  const int tid = threadIdx.x;
  const int m0 = blockIdx.y << 6, n0 = blockIdx.x << 6;
  const int tx = tid & 15, ty = tid >> 4;
  const int lr = tid >> 2, lk = (tid & 3) << 2;
  float accg[4][4] = {}, accu[4][4] = {};
  const float* xp = X + (size_t)(m0 + lr) * D + lk;
  const float* wgp = Wg + (size_t)(n0 + lr) * D + lk;
  const float* wup = Bu + (size_t)(n0 + lr) * D + lk;
  for (int k0 = 0; k0 < D; k0 += 16) {
    float4 xv = *(const float4*)(xp + k0);
    float4 gv = *(const float4*)(wgp + k0);
    float4 uv = *(const float4*)(wup + k0);
    __syncthreads();
    Xs[lk + 0][lr] = xv.x; Xs[lk + 1][lr] = xv.y; Xs[lk + 2][lr] = xv.z; Xs[lk + 3][lr] = xv.w;
    Wgs[lk + 0][lr] = gv.x; Wgs[lk + 1][lr] = gv.y; Wgs[lk + 2][lr] = gv.z; Wgs[lk + 3][lr] = gv.w;
    Wus[lk + 0][lr] = uv.x; Wus[lk + 1][lr] = uv.y; Wus[lk + 2][lr] = uv.z; Wus[lk + 3][lr] = uv.w;
    __syncthreads();
#pragma unroll
    for (int k = 0; k < 16; ++k) {
      float4 av = *(const float4*)&Xs[k][tx << 2];
      float4 g4 = *(const float4*)&Wgs[k][ty << 2];
      float4 u4 = *(const float4*)&Wus[k][ty << 2];
      const float aa[4] = {av.x, av.y, av.z, av.w};
      const float gg[4] = {g4.x, g4.y, g4.z, g4.w};
      const float uu[4] = {u4.x, u4.y, u4.z, u4.w};
#pragma unroll
      for (int i = 0; i < 4; ++i)
#pragma unroll
        for (int jj = 0; jj < 4; ++jj) {
          accg[i][jj] += aa[i] * gg[jj];
          accu[i][jj] += aa[i] * uu[jj];
        }
    }
  }
  const int nc = n0 + (ty << 2);
#pragma unroll
  for (int i = 0; i < 4; ++i) {
    const int row = m0 + (tx << 2) + i;
    ushort4 og, ou;
    {
      float z0 = accg[i][0] + bg[nc + 0], z1 = accg[i][1] + bg[nc + 1];
      float z2 = accg[i][2] + bg[nc + 2], z3 = accg[i][3] + bg[nc + 3];
      og.x = f2bf(1.0f / (1.0f + __expf(-z0)));
      og.y = f2bf(1.0f / (1.0f + __expf(-z1)));
      og.z = f2bf(1.0f / (1.0f + __expf(-z2)));
      og.w = f2bf(1.0f / (1.0f + __expf(-z3)));
    }
    ou.x = f2bf(accu[i][0]); ou.y = f2bf(accu[i][1]);
    ou.z = f2bf(accu[i][2]); ou.w = f2bf(accu[i][3]);
    *(ushort4*)&G[(size_t)row * D + nc] = og;
    *(ushort4*)&U[(size_t)row * D + nc] = ou;
  }
}

// ---------------- Scan v3: 1024 independent waves, tagged-granule exchange ----------------
__global__ __launch_bounds__(256, 1) void k_scan(
    const float* __restrict__ A, const float* __restrict__ inp,
    const uint16_t* __restrict__ gate, const uint16_t* __restrict__ u,
    float* __restrict__ slice) {
  const int tid = threadIdx.x;
  const int w = tid >> 6, l = tid & 63;
  const int gw = (blockIdx.x << 2) + w;   // global wave 0..1023
  const int b = gw >> 7;                  // batch 0..7 (128 waves each)
  const int j0 = (gw & 127) << 3;         // this wave's 8 output cols

  // A fragments: Areg[c][k] = A[j0+c][128k+2l .. +1]  (128 VGPRs)
  float2 Areg[8][8];
#pragma unroll
  for (int c = 0; c < 8; ++c)
#pragma unroll
    for (int k = 0; k < 8; ++k)
      Areg[c][k] = *(const float2*)&A[(size_t)(j0 + c) * D + (k << 7) + (l << 1)];
  // PIN: opacify so the compiler cannot rematerialize (re-load) A inside the
  // t-loop. v2 allocated only 100 VGPRs -> A was being re-fetched every step,
  // putting ~64 L2 loads on the per-step critical path.
#pragma unroll
  for (int c = 0; c < 8; ++c)
#pragma unroll
    for (int k = 0; k < 8; ++k)
      asm volatile("" : "+v"(Areg[c][k].x), "+v"(Areg[c][k].y));

  unsigned long long* slice8 = (unsigned long long*)slice;
  const int jc = j0 + l;  // valid for l<8: lane's output column

  for (int t = 0; t < SEQ; ++t) {
    // prefetch this step's gate/u/inp (normal cached loads, issued before spin)
    float pg = 0.f, pu = 0.f, pi = 0.f;
    if (l < 8) {
      const size_t ridx = ((size_t)(b << 12) + t) * D + jc;
      pg = bf2f(gate[ridx]);
      pu = bf2f(u[ridx]);
      pi = inp[ridx];
    }
    asm volatile("" : "+v"(pg), "+v"(pu), "+v"(pi));  // force issue before spin

    float ax[8] = {}, ay[8] = {};
    if (t > 0) {
      const unsigned long long* src8 =
          slice8 + (((size_t)(t - 1) * NBATCH + b) << 9);
      const uint32_t tagv = (uint32_t)(((t - 1) & 7) | 8);
      unsigned long long vv[8];  // lane l holds granules {l+64k} = floats {128k+2l,+1}
      while (true) {
        bool ok = true;
#pragma unroll
        for (int k = 0; k < 8; ++k)
          vv[k] = __hip_atomic_load(&src8[(k << 6) + l],
                                    __ATOMIC_RELAXED, __HIP_MEMORY_SCOPE_AGENT);
#pragma unroll
        for (int k = 0; k < 8; ++k)
          ok &= (((uint32_t)vv[k] & 15u) == tagv);
        if (__all(ok)) break;
        __builtin_amdgcn_s_sleep(1);
      }
#pragma unroll
      for (int k = 0; k < 8; ++k) {
        const float2 sv = __builtin_bit_cast(float2, vv[k]);
#pragma unroll
        for (int c = 0; c < 8; ++c) {
          ax[c] = __builtin_fmaf(sv.x, Areg[c][k].x, ax[c]);
          ay[c] = __builtin_fmaf(sv.y, Areg[c][k].y, ay[c]);
        }
      }
    }
    float dot[8];
#pragma unroll
    for (int c = 0; c < 8; ++c) dot[c] = ax[c] + ay[c];

    // Allreduce: full butterfly on lane bits 3..5, then reduce-scatter on
    // bits 0..2 (halve value count per stage). Every lane ends with the
    // complete sum for its column c = l&7 -- no select chain needed.
#pragma unroll
    for (int off = 8; off < 64; off <<= 1)
#pragma unroll
      for (int c = 0; c < 8; ++c) dot[c] += __shfl_xor(dot[c], off, 64);
    const bool b4 = (l & 4) != 0, b2 = (l & 2) != 0, b1 = (l & 1) != 0;
    float r4[4];
#pragma unroll
    for (int i = 0; i < 4; ++i) {
      const float keep = b4 ? dot[4 + i] : dot[i];
      const float send = b4 ? dot[i] : dot[4 + i];
      r4[i] = keep + __shfl_xor(send, 4, 64);
    }
    float r2[2];
#pragma unroll
    for (int i = 0; i < 2; ++i) {
      const float keep = b2 ? r4[2 + i] : r4[i];
      const float send = b2 ? r4[i] : r4[2 + i];
      r2[i] = keep + __shfl_xor(send, 2, 64);
    }
    const float k1 = b1 ? r2[1] : r2[0];
    const float s1 = b1 ? r2[0] : r2[1];
    const float dsel = k1 + __shfl_xor(s1, 1, 64);

    const float sv = fast_tanh(dsel + pu);
    const float val = pg * sv + (1.f - pg) * pi;  // meaningful on l<8 only

    // pack col pairs into one 8B atomic store: low float carries the epoch tag
    const float valn = __shfl_xor(val, 1, 64);
    if ((l < 8) && ((l & 1) == 0)) {
      const uint32_t tagst = (uint32_t)((t & 7) | 8);
      const uint32_t lo = (__builtin_bit_cast(uint32_t, val) & ~15u) | tagst;
      const uint32_t hi = __builtin_bit_cast(uint32_t, valn);
      const unsigned long long pk = ((unsigned long long)hi << 32) | lo;
      __hip_atomic_store(&slice8[(((size_t)t * NBATCH + b) << 9) + ((j0 + l) >> 1)],
                         pk, __ATOMIC_RELAXED, __HIP_MEMORY_SCOPE_AGENT);
    }
    // no drain, no flag, no barrier: the tag IS the validity bit.
  }
}

// ---------------- GEMM 3: out = states @ W_out^T + b_out (reads slice[t][b][k]) ----------------
__global__ __launch_bounds__(256) void k_gemm_out(
    const float* __restrict__ S, const float* __restrict__ W,
    const float* __restrict__ bias, float* __restrict__ Y) {
  __shared__ float Xs[16][68];
  __shared__ float Ws[16][68];
  const int tid = threadIdx.x;
  const int m0 = blockIdx.y << 6, n0 = blockIdx.x << 6;
  const int tx = tid & 15, ty = tid >> 4;
  const int lr = tid >> 2, lk = (tid & 3) << 2;
  const int bb_ = m0 >> 12;          // batch (m-block never crosses batch: 4096 % 64 == 0)
  const int t0 = (m0 & 4095) + lr;   // time index of this loader row
  float acc[4][4] = {};
  const float* wp = W + (size_t)(n0 + lr) * D + lk;
  for (int k0 = 0; k0 < D; k0 += 16) {
    const int k = k0 + lk;
    // states(r=b*4096+t, k) lives at slice[(t*8+b)*1024 + k]
    float4 xv = *(const float4*)(S + (((size_t)t0 * NBATCH + bb_) << 10) + k);
    float4 wv = *(const float4*)(wp + k0);
    __syncthreads();
    Xs[lk + 0][lr] = xv.x; Xs[lk + 1][lr] = xv.y; Xs[lk + 2][lr] = xv.z; Xs[lk + 3][lr] = xv.w;
    Ws[lk + 0][lr] = wv.x; Ws[lk + 1][lr] = wv.y; Ws[lk + 2][lr] = wv.z; Ws[lk + 3][lr] = wv.w;
    __syncthreads();
#pragma unroll
    for (int kk = 0; kk < 16; ++kk) {
      float4 av = *(const float4*)&Xs[kk][tx << 2];
      float4 bv = *(const float4*)&Ws[kk][ty << 2];
      const float aa[4] = {av.x, av.y, av.z, av.w};
      const float bb[4] = {bv.x, bv.y, bv.z, bv.w};
#pragma unroll
      for (int i = 0; i < 4; ++i)
#pragma unroll
        for (int jj = 0; jj < 4; ++jj) acc[i][jj] += aa[i] * bb[jj];
    }
  }
  const int nc = n0 + (ty << 2);
#pragma unroll
  for (int i = 0; i < 4; ++i) {
    const int row = m0 + (tx << 2) + i;
    float4 o;
    o.x = acc[i][0] + bias[nc + 0];
    o.y = acc[i][1] + bias[nc + 1];
    o.z = acc[i][2] + bias[nc + 2];
    o.w = acc[i][3] + bias[nc + 3];
    *(float4*)&Y[(size_t)row * D + nc] = o;
  }
}

extern "C" void kernel_launch(void* const* d_in, const int* in_sizes, int n_in,
                              void* d_out, int out_size, void* d_ws, size_t ws_size,
                              hipStream_t stream) {
  const float* x      = (const float*)d_in[0];
  const float* A      = (const float*)d_in[1];
  const float* B      = (const float*)d_in[2];
  const float* W_in   = (const float*)d_in[3];
  const float* b_in   = (const float*)d_in[4];
  const float* W_gate = (const float*)d_in[5];
  const float* b_gate = (const float*)d_in[6];
  const float* W_out  = (const float*)d_in[7];
  const float* b_out  = (const float*)d_in[8];
  float* out = (float*)d_out;
  char* ws = (char*)d_ws;

  uint16_t* gate = (uint16_t*)ws;
  uint16_t* u    = (uint16_t*)(ws + GATE_BYTES);
  float* slice   = (float*)(ws + GATE_BYTES + U_BYTES);

  // Clear stale epoch tags from previous launches (tag nibble 0 is never valid).
  hipMemsetAsync(slice, 0, SLICE_BYTES, stream);

  dim3 gg(D / 64, NROWS / 64);
  // inp parked in d_out (fp32) until k_gemm_out overwrites it.
  k_gemm_in<<<gg, 256, 0, stream>>>(x, W_in, b_in, out);
  k_gemm_gate_u<<<gg, 256, 0, stream>>>(out, W_gate, b_gate, B, gate, u);
  k_scan<<<256, 256, 0, stream>>>(A, out, gate, u, slice);
  k_gemm_out<<<gg, 256, 0, stream>>>(slice, W_out, b_out, out);
}

// Round 3
// 9763.177 us; speedup vs baseline: 1.2739x; 1.2739x over previous
//
#include <hip/hip_runtime.h>
#include <stdint.h>

// MambaBlock: DIM=1024, BATCH=8, SEQ=4096.
//   inp  = x @ W_in^T + b_in                  (fp32, parked in d_out)
//   gate = sigmoid(inp @ W_gate^T + b_gate)   (bf16 in ws)
//   u    = inp @ B^T                          (bf16 in ws)
//   scan: s_t = g*tanh(s_{t-1}@A^T + u_t) + (1-g)*inp_t   (fp32, tagged-granule LLC exchange)
//   out  = states @ W_out^T + b_out           (fp32 -> d_out)
//
// Scan v4: cooperative-poll + LDS broadcast + XCD-local batches.
//   256 WGs x 256 thr. WG: batch b = blockIdx&7 (XCD-local), widx = blockIdx>>3.
//   WG owns 32 cols; wave w owns 8 cols j0 = widx*32 + 8w.
//   Exchange: slice[t][b][1024] fp32, 8B tagged granules (epoch tag (t&7)|8 in
//   low float's mantissa nibble; memset clears stale tags; every address written
//   once per run). Each wave polls a DISJOINT QUARTER of the state (2 granules/
//   lane = 1KB/round, was 4KB/wave) -> 4x less LLC poll traffic; granules land
//   in LDS (double-buffered, 1 barrier/step) and all 4 waves read state from LDS.
//   Tail: packed pk_fma dots + 10-shuffle reduce-scatter (small offsets first).

#define D 1024
#define NBATCH 8
#define SEQ 4096
#define NROWS 32768  // NBATCH*SEQ

static constexpr size_t GATE_BYTES  = (size_t)NROWS * D * 2;          // 64 MiB bf16
static constexpr size_t U_BYTES     = (size_t)NROWS * D * 2;          // 64 MiB bf16
static constexpr size_t SLICE_BYTES = (size_t)SEQ * NBATCH * D * 4;   // 128 MiB fp32

typedef float f32x2 __attribute__((ext_vector_type(2)));

__device__ __forceinline__ float bf2f(uint16_t h) {
  uint32_t u = ((uint32_t)h) << 16;
  return __builtin_bit_cast(float, u);
}
__device__ __forceinline__ uint16_t f2bf(float f) {
  uint32_t u = __builtin_bit_cast(uint32_t, f);
  u = u + 0x7fffu + ((u >> 16) & 1u);   // RNE
  return (uint16_t)(u >> 16);
}

// branch-free tanh: 1 - 2/(e^{2x}+1); saturates correctly at +-1 via inf/0.
__device__ __forceinline__ float fast_tanh(float x) {
  const float e = __expf(2.0f * x);
  return 1.0f - 2.0f / (e + 1.0f);
}

// ---------------- GEMM 1: inp = x @ W_in^T + b_in (fp32 out) ----------------
__global__ __launch_bounds__(256) void k_gemm_in(
    const float* __restrict__ X, const float* __restrict__ W,
    const float* __restrict__ bias, float* __restrict__ Y) {
  __shared__ float Xs[16][68];
  __shared__ float Ws[16][68];
  const int tid = threadIdx.x;
  const int m0 = blockIdx.y << 6, n0 = blockIdx.x << 6;
  const int tx = tid & 15, ty = tid >> 4;
  const int lr = tid >> 2, lk = (tid & 3) << 2;
  float acc[4][4] = {};
  const float* xp = X + (size_t)(m0 + lr) * D + lk;
  const float* wp = W + (size_t)(n0 + lr) * D + lk;
  for (int k0 = 0; k0 < D; k0 += 16) {
    float4 xv = *(const float4*)(xp + k0);
    float4 wv = *(const float4*)(wp + k0);
    __syncthreads();
    Xs[lk + 0][lr] = xv.x; Xs[lk + 1][lr] = xv.y; Xs[lk + 2][lr] = xv.z; Xs[lk + 3][lr] = xv.w;
    Ws[lk + 0][lr] = wv.x; Ws[lk + 1][lr] = wv.y; Ws[lk + 2][lr] = wv.z; Ws[lk + 3][lr] = wv.w;
    __syncthreads();
#pragma unroll
    for (int k = 0; k < 16; ++k) {
      float4 av = *(const float4*)&Xs[k][tx << 2];
      float4 bv = *(const float4*)&Ws[k][ty << 2];
      const float aa[4] = {av.x, av.y, av.z, av.w};
      const float bb[4] = {bv.x, bv.y, bv.z, bv.w};
#pragma unroll
      for (int i = 0; i < 4; ++i)
#pragma unroll
        for (int jj = 0; jj < 4; ++jj) acc[i][jj] += aa[i] * bb[jj];
    }
  }
  const int nc = n0 + (ty << 2);
#pragma unroll
  for (int i = 0; i < 4; ++i) {
    const int row = m0 + (tx << 2) + i;
    float4 o;
    o.x = acc[i][0] + bias[nc + 0];
    o.y = acc[i][1] + bias[nc + 1];
    o.z = acc[i][2] + bias[nc + 2];
    o.w = acc[i][3] + bias[nc + 3];
    *(float4*)&Y[(size_t)row * D + nc] = o;
  }
}

// ------- GEMM 2 (fused): gate = sigmoid(inp@Wg^T + bg), u = inp@B^T (bf16 out) -------
__global__ __launch_bounds__(256) void k_gemm_gate_u(
    const float* __restrict__ X, const float* __restrict__ Wg,
    const float* __restrict__ bg, const float* __restrict__ Bu,
    uint16_t* __restrict__ G, uint16_t* __restrict__ U) {
  __shared__ float Xs[16][68];
  __shared__ float Wgs[16][68];
  __shared__ float Wus[16][68];
  const int tid = threadIdx.x;
  const int m0 = blockIdx.y << 6, n0 = blockIdx.x << 6;
  const int tx = tid & 15, ty = tid >> 4;
  const int lr = tid >> 2, lk = (tid & 3) << 2;
  float accg[4][4] = {}, accu[4][4] = {};
  const float* xp = X + (size_t)(m0 + lr) * D + lk;
  const float* wgp = Wg + (size_t)(n0 + lr) * D + lk;
  const float* wup = Bu + (size_t)(n0 + lr) * D + lk;
  for (int k0 = 0; k0 < D; k0 += 16) {
    float4 xv = *(const float4*)(xp + k0);
    float4 gv = *(const float4*)(wgp + k0);
    float4 uv = *(const float4*)(wup + k0);
    __syncthreads();
    Xs[lk + 0][lr] = xv.x; Xs[lk + 1][lr] = xv.y; Xs[lk + 2][lr] = xv.z; Xs[lk + 3][lr] = xv.w;
    Wgs[lk + 0][lr] = gv.x; Wgs[lk + 1][lr] = gv.y; Wgs[lk + 2][lr] = gv.z; Wgs[lk + 3][lr] = gv.w;
    Wus[lk + 0][lr] = uv.x; Wus[lk + 1][lr] = uv.y; Wus[lk + 2][lr] = uv.z; Wus[lk + 3][lr] = uv.w;
    __syncthreads();
#pragma unroll
    for (int k = 0; k < 16; ++k) {
      float4 av = *(const float4*)&Xs[k][tx << 2];
      float4 g4 = *(const float4*)&Wgs[k][ty << 2];
      float4 u4 = *(const float4*)&Wus[k][ty << 2];
      const float aa[4] = {av.x, av.y, av.z, av.w};
      const float gg[4] = {g4.x, g4.y, g4.z, g4.w};
      const float uu[4] = {u4.x, u4.y, u4.z, u4.w};
#pragma unroll
      for (int i = 0; i < 4; ++i)
#pragma unroll
        for (int jj = 0; jj < 4; ++jj) {
          accg[i][jj] += aa[i] * gg[jj];
          accu[i][jj] += aa[i] * uu[jj];
        }
    }
  }
  const int nc = n0 + (ty << 2);
#pragma unroll
  for (int i = 0; i < 4; ++i) {
    const int row = m0 + (tx << 2) + i;
    ushort4 og, ou;
    {
      float z0 = accg[i][0] + bg[nc + 0], z1 = accg[i][1] + bg[nc + 1];
      float z2 = accg[i][2] + bg[nc + 2], z3 = accg[i][3] + bg[nc + 3];
      og.x = f2bf(1.0f / (1.0f + __expf(-z0)));
      og.y = f2bf(1.0f / (1.0f + __expf(-z1)));
      og.z = f2bf(1.0f / (1.0f + __expf(-z2)));
      og.w = f2bf(1.0f / (1.0f + __expf(-z3)));
    }
    ou.x = f2bf(accu[i][0]); ou.y = f2bf(accu[i][1]);
    ou.z = f2bf(accu[i][2]); ou.w = f2bf(accu[i][3]);
    *(ushort4*)&G[(size_t)row * D + nc] = og;
    *(ushort4*)&U[(size_t)row * D + nc] = ou;
  }
}

// ---------------- Scan v4: cooperative poll + LDS broadcast ----------------
// LDS index padding: granule g -> g + g/16 (breaks 8B-stride 4-way bank alias).
__device__ __forceinline__ int pidx(int g) { return g + (g >> 4); }

__global__ __launch_bounds__(256, 1)
__attribute__((amdgpu_waves_per_eu(1, 1)))
void k_scan(
    const float* __restrict__ A, const float* __restrict__ inp,
    const uint16_t* __restrict__ gate, const uint16_t* __restrict__ u,
    float* __restrict__ slice) {
  __shared__ f32x2 Ss[2][544];   // 512 granules + pad, double-buffered (8.7 KB)
  const int tid = threadIdx.x;
  const int w = tid >> 6, l = tid & 63;
  const int b = blockIdx.x & 7;        // batch: XCD-local (block i -> XCD i%8)
  const int widx = blockIdx.x >> 3;    // 0..31 within batch
  const int j0 = (widx << 5) + (w << 3);  // wave's 8 output cols

  // A fragments: Areg[c][k] = {A[j0+c][128k+2l], A[j0+c][128k+2l+1]}
  f32x2 Areg[8][8];
#pragma unroll
  for (int c = 0; c < 8; ++c)
#pragma unroll
    for (int k = 0; k < 8; ++k) {
      const float2 t2 = *(const float2*)&A[(size_t)(j0 + c) * D + (k << 7) + (l << 1)];
      Areg[c][k] = f32x2{t2.x, t2.y};
    }
#pragma unroll
  for (int c = 0; c < 8; ++c)
#pragma unroll
    for (int k = 0; k < 8; ++k)
      asm volatile("" : "+v"(Areg[c][k].x), "+v"(Areg[c][k].y));

  unsigned long long* slice8 = (unsigned long long*)slice;
  const int jc = j0 + l;               // valid for l<8: lane's output column
  const int g0 = (w << 7) + l;         // this wave's poll quarter: granules g0, g0+64
  const int pg0 = pidx(g0), pg1 = pidx(g0 + 64);

  for (int t = 0; t < SEQ; ++t) {
    // prefetch this step's gate/u/inp (cached loads, issued before the spin)
    float pg = 0.f, pu = 0.f, pi = 0.f;
    if (l < 8) {
      const size_t ridx = ((size_t)(b << 12) + t) * D + jc;
      pg = bf2f(gate[ridx]);
      pu = bf2f(u[ridx]);
      pi = inp[ridx];
    }
    asm volatile("" : "+v"(pg), "+v"(pu), "+v"(pi));

    float f = 0.f;
    if (t > 0) {
      // ---- cooperative poll: this wave owns granules [128w, 128w+128) ----
      const unsigned long long* src8 =
          slice8 + (((size_t)(t - 1) * NBATCH + b) << 9);
      const uint32_t tagv = (uint32_t)(((t - 1) & 7) | 8);
      unsigned long long v0, v1;
      while (true) {
        v0 = __hip_atomic_load(&src8[g0],      __ATOMIC_RELAXED, __HIP_MEMORY_SCOPE_AGENT);
        v1 = __hip_atomic_load(&src8[g0 + 64], __ATOMIC_RELAXED, __HIP_MEMORY_SCOPE_AGENT);
        const bool ok = (((uint32_t)v0 & 15u) == tagv) & (((uint32_t)v1 & 15u) == tagv);
        if (__all(ok)) break;
        __builtin_amdgcn_s_sleep(1);
      }
      f32x2* buf = Ss[t & 1];
      buf[pg0] = __builtin_bit_cast(f32x2, v0);
      buf[pg1] = __builtin_bit_cast(f32x2, v1);
      __syncthreads();   // all quarters staged

      // ---- packed dot: acc[c] += s_pair * A_pair (v_pk_fma_f32) ----
      f32x2 acc[8];
#pragma unroll
      for (int c = 0; c < 8; ++c) acc[c] = f32x2{0.f, 0.f};
#pragma unroll
      for (int k = 0; k < 8; ++k) {
        const f32x2 sv = buf[pidx((k << 6) + l)];
#pragma unroll
        for (int c = 0; c < 8; ++c) acc[c] += sv * Areg[c][k];
      }
      float p[8];
#pragma unroll
      for (int c = 0; c < 8; ++c) p[c] = acc[c].x + acc[c].y;

      // ---- reduce-scatter (small offsets first): 10 shuffles total ----
      // lane l ends with the FULL dot for col (l&7), replicated across lane groups.
      const bool b0 = (l & 1) != 0, b1 = (l & 2) != 0, b2 = (l & 4) != 0;
      float r[4];
#pragma unroll
      for (int i = 0; i < 4; ++i) {
        const float keep = b0 ? p[2 * i + 1] : p[2 * i];
        const float send = b0 ? p[2 * i] : p[2 * i + 1];
        r[i] = keep + __shfl_xor(send, 1, 64);
      }
      float q[2];
#pragma unroll
      for (int m = 0; m < 2; ++m) {
        const float keep = b1 ? r[2 * m + 1] : r[2 * m];
        const float send = b1 ? r[2 * m] : r[2 * m + 1];
        q[m] = keep + __shfl_xor(send, 2, 64);
      }
      {
        const float keep = b2 ? q[1] : q[0];
        const float send = b2 ? q[0] : q[1];
        f = keep + __shfl_xor(send, 4, 64);
      }
      f += __shfl_xor(f, 8, 64);
      f += __shfl_xor(f, 16, 64);
      f += __shfl_xor(f, 32, 64);
    }

    const float sv = fast_tanh(f + pu);
    const float val = pg * sv + (1.f - pg) * pi;   // meaningful on l<8 only

    // pack col pairs into one 8B atomic store: low float carries the epoch tag
    const float valn = __shfl_xor(val, 1, 64);
    if ((l < 8) && ((l & 1) == 0)) {
      const uint32_t tagst = (uint32_t)((t & 7) | 8);
      const uint32_t lo = (__builtin_bit_cast(uint32_t, val) & ~15u) | tagst;
      const uint32_t hi = __builtin_bit_cast(uint32_t, valn);
      const unsigned long long pk = ((unsigned long long)hi << 32) | lo;
      __hip_atomic_store(&slice8[(((size_t)t * NBATCH + b) << 9) + ((j0 + l) >> 1)],
                         pk, __ATOMIC_RELAXED, __HIP_MEMORY_SCOPE_AGENT);
    }
    // no drain, no flag: the in-granule tag IS the validity bit.
  }
}

// ---------------- GEMM 3: out = states @ W_out^T + b_out (reads slice[t][b][k]) ----------------
__global__ __launch_bounds__(256) void k_gemm_out(
    const float* __restrict__ S, const float* __restrict__ W,
    const float* __restrict__ bias, float* __restrict__ Y) {
  __shared__ float Xs[16][68];
  __shared__ float Ws[16][68];
  const int tid = threadIdx.x;
  const int m0 = blockIdx.y << 6, n0 = blockIdx.x << 6;
  const int tx = tid & 15, ty = tid >> 4;
  const int lr = tid >> 2, lk = (tid & 3) << 2;
  const int bb_ = m0 >> 12;          // batch (m-block never crosses batch: 4096 % 64 == 0)
  const int t0 = (m0 & 4095) + lr;   // time index of this loader row
  float acc[4][4] = {};
  const float* wp = W + (size_t)(n0 + lr) * D + lk;
  for (int k0 = 0; k0 < D; k0 += 16) {
    const int k = k0 + lk;
    // states(r=b*4096+t, k) lives at slice[(t*8+b)*1024 + k]
    float4 xv = *(const float4*)(S + (((size_t)t0 * NBATCH + bb_) << 10) + k);
    float4 wv = *(const float4*)(wp + k0);
    __syncthreads();
    Xs[lk + 0][lr] = xv.x; Xs[lk + 1][lr] = xv.y; Xs[lk + 2][lr] = xv.z; Xs[lk + 3][lr] = xv.w;
    Ws[lk + 0][lr] = wv.x; Ws[lk + 1][lr] = wv.y; Ws[lk + 2][lr] = wv.z; Ws[lk + 3][lr] = wv.w;
    __syncthreads();
#pragma unroll
    for (int kk = 0; kk < 16; ++kk) {
      float4 av = *(const float4*)&Xs[kk][tx << 2];
      float4 bv = *(const float4*)&Ws[kk][ty << 2];
      const float aa[4] = {av.x, av.y, av.z, av.w};
      const float bb[4] = {bv.x, bv.y, bv.z, bv.w};
#pragma unroll
      for (int i = 0; i < 4; ++i)
#pragma unroll
        for (int jj = 0; jj < 4; ++jj) acc[i][jj] += aa[i] * bb[jj];
    }
  }
  const int nc = n0 + (ty << 2);
#pragma unroll
  for (int i = 0; i < 4; ++i) {
    const int row = m0 + (tx << 2) + i;
    float4 o;
    o.x = acc[i][0] + bias[nc + 0];
    o.y = acc[i][1] + bias[nc + 1];
    o.z = acc[i][2] + bias[nc + 2];
    o.w = acc[i][3] + bias[nc + 3];
    *(float4*)&Y[(size_t)row * D + nc] = o;
  }
}

extern "C" void kernel_launch(void* const* d_in, const int* in_sizes, int n_in,
                              void* d_out, int out_size, void* d_ws, size_t ws_size,
                              hipStream_t stream) {
  const float* x      = (const float*)d_in[0];
  const float* A      = (const float*)d_in[1];
  const float* B      = (const float*)d_in[2];
  const float* W_in   = (const float*)d_in[3];
  const float* b_in   = (const float*)d_in[4];
  const float* W_gate = (const float*)d_in[5];
  const float* b_gate = (const float*)d_in[6];
  const float* W_out  = (const float*)d_in[7];
  const float* b_out  = (const float*)d_in[8];
  float* out = (float*)d_out;
  char* ws = (char*)d_ws;

  uint16_t* gate = (uint16_t*)ws;
  uint16_t* u    = (uint16_t*)(ws + GATE_BYTES);
  float* slice   = (float*)(ws + GATE_BYTES + U_BYTES);

  // Clear stale epoch tags from previous launches (tag nibble 0 is never valid).
  hipMemsetAsync(slice, 0, SLICE_BYTES, stream);

  dim3 gg(D / 64, NROWS / 64);
  // inp parked in d_out (fp32) until k_gemm_out overwrites it.
  k_gemm_in<<<gg, 256, 0, stream>>>(x, W_in, b_in, out);
  k_gemm_gate_u<<<gg, 256, 0, stream>>>(out, W_gate, b_gate, B, gate, u);
  k_scan<<<256, 256, 0, stream>>>(A, out, gate, u, slice);
  k_gemm_out<<<gg, 256, 0, stream>>>(slice, W_out, b_out, out);
}